// Round 8
// baseline (4402.062 us; speedup 1.0000x reference)
//
#include <hip/hip_runtime.h>
#include <math.h>
#include <stdint.h>

// Dims
#define BN    256      // B*N
#define UVD   49       // U*V
#define STD_  64       // S*T
#define CHD   8
#define AD    98
#define MD    128
#define CD    16

#define ZSZ   (BN*AD*MD*CD)      // 51,380,224 elements
#define T2SZ  (BN*AD*STD_*CHD)   // 12,845,056
#define PVSZ  (AD*MD*CD)         // 200,704

typedef unsigned short u16;
typedef __attribute__((ext_vector_type(8))) short bf16x8;
typedef __attribute__((ext_vector_type(4))) float f32x4;

// ---- bf16 helpers (internal storage bf16, compute fp32) ----
__device__ __forceinline__ float bflo(uint32_t u) {
    return __builtin_bit_cast(float, u << 16);
}
__device__ __forceinline__ float bfhi(uint32_t u) {
    return __builtin_bit_cast(float, u & 0xFFFF0000u);
}
__device__ __forceinline__ uint32_t packbf(float lo, float hi) {  // RNE pack 2 fp32 -> 2 bf16
    uint32_t a = __builtin_bit_cast(uint32_t, lo);
    uint32_t b = __builtin_bit_cast(uint32_t, hi);
    a = (a + 0x7FFFu + ((a >> 16) & 1u)) >> 16;
    b = (b + 0x7FFFu + ((b >> 16) & 1u)) >> 16;
    return a | (b << 16);
}
__device__ __forceinline__ u16 bf1(float f) {   // RNE fp32 -> bf16
    uint32_t a = __builtin_bit_cast(uint32_t, f);
    a = (a + 0x7FFFu + ((a >> 16) & 1u)) >> 16;
    return (u16)a;
}

__device__ __forceinline__ void fma4(float4& a, const float4& v, float s) {
    a.x = fmaf(v.x, s, a.x); a.y = fmaf(v.y, s, a.y);
    a.z = fmaf(v.z, s, a.z); a.w = fmaf(v.w, s, a.w);
}

__device__ __forceinline__ uint32_t hsh(uint32_t x) {
    x ^= x >> 16; x *= 0x7feb352dU;
    x ^= x >> 15; x *= 0x846ca68bU;
    x ^= x >> 16; return x;
}

__device__ __forceinline__ float blockReduceSum256(float s) {
    __shared__ float sw[4];
    #pragma unroll
    for (int o = 32; o > 0; o >>= 1) s += __shfl_down(s, o, 64);
    int lane = threadIdx.x & 63, wi = threadIdx.x >> 6;
    if (lane == 0) sw[wi] = s;
    __syncthreads();
    return sw[0] + sw[1] + sw[2] + sw[3];
}

// ---------------- prep: fragment-ordered ds (bf16) + Gram matrices ----------------

__global__ __launch_bounds__(256) void k_prep(const float* __restrict__ da, const float* __restrict__ ds,
                                              const float* __restrict__ dc,
                                              u16* __restrict__ dsAg, u16* __restrict__ dsCg,
                                              float* __restrict__ Ga, float* __restrict__ Gs,
                                              float* __restrict__ Gc) {
    int i = blockIdx.x * 256 + threadIdx.x;
    if (i < 8192) {                        // stage-A frags: A[m][k=st]
        int f = i >> 9, r = i & 511, L = r >> 3, j = r & 7;
        int mt = f >> 1, kc = f & 1;
        int m = mt * 16 + (L & 15), st = kc * 32 + (L >> 4) * 8 + j;
        dsAg[i] = bf1(ds[m * 64 + st]);
        return;
    }
    int i2 = i - 8192;
    if (i2 < 8192) {                       // stage-C frags: A2[st][k=m]
        int f = i2 >> 9, r = i2 & 511, L = r >> 3, j = r & 7;
        int mt2 = f >> 2, kc = f & 3;
        int st = mt2 * 16 + (L & 15), m = kc * 32 + (L >> 4) * 8 + j;
        dsCg[i2] = bf1(ds[m * 64 + st]);
        return;
    }
    int jg = i2 - 8192;
    if (jg < 9604) {                       // Ga 98x98 (symmetric)
        int a = jg / 98, b = jg % 98;
        float s = 0.f;
        for (int uv = 0; uv < 49; ++uv) s = fmaf(da[a * 49 + uv], da[b * 49 + uv], s);
        Ga[jg] = s;
        return;
    }
    int k = jg - 9604;
    if (k < 16384) {                       // Gs 128x128
        int m = k >> 7, n = k & 127;
        float s = 0.f;
        for (int st = 0; st < 64; ++st) s = fmaf(ds[m * 64 + st], ds[n * 64 + st], s);
        Gs[k] = s;
        return;
    }
    int l = k - 16384;
    if (l < 256) {                         // Gc 16x16
        int c = l >> 4, d = l & 15;
        float s = 0.f;
        for (int h = 0; h < 8; ++h) s = fmaf(dc[c * 8 + h], dc[d * 8 + h], s);
        Gc[l] = s;
    }
}

// ---------------- one-time: xan = -adj_a(x), h-major bf16 ----------------

__global__ __launch_bounds__(256) void k_xa(const float* __restrict__ xg, const float* __restrict__ da,
                                            u16* __restrict__ xan) {
    __shared__ float l_r[49 * 68];     // 13.0 KB
    int ch = blockIdx.x, bn = blockIdx.y, t = threadIdx.x;   // ch = h (0..7)
    int base = ch * 64;
    size_t xbase = (size_t)bn * 25088;
    for (int e2 = t; e2 < 1568; e2 += 256) {
        int uv = e2 >> 5, i2 = (e2 & 31) * 2;
        float x0 = xg[xbase + uv * 512 + i2 * 8 + ch];
        float x1 = xg[xbase + uv * 512 + (i2 + 1) * 8 + ch];
        l_r[uv * 68 + i2]     = -x0;
        l_r[uv * 68 + i2 + 1] = -x1;
    }
    __syncthreads();
    for (int e2 = t; e2 < 3136; e2 += 256) {
        int a = e2 >> 5, i2 = (e2 & 31) * 2;
        float s0 = 0.f, s1 = 0.f;
        for (int uv = 0; uv < 49; ++uv) {
            float w = da[a * 49 + uv];
            s0 = fmaf(l_r[uv * 68 + i2], w, s0);
            s1 = fmaf(l_r[uv * 68 + i2 + 1], w, s1);
        }
        *(uint32_t*)&xan[(size_t)(bn * 98 + a) * 512 + base + i2] = packbf(s0, s1);
    }
}

// ---------------- joint 10-iter power iteration (fused, lazy-normalized) ----------------
// State: (wv, part). Normalized v = wv / sqrt(sum(part)).

__global__ __launch_bounds__(256) void k_v0(float* __restrict__ wv, float* __restrict__ part) {
    int b = blockIdx.x, t = threadIdx.x;
    float ssq = 0.f;
    for (int i = b * 1568 + t; i < (b + 1) * 1568; i += 256) {
        uint32_t h1 = hsh((uint32_t)(i * 2 + 1));
        uint32_t h2 = hsh((uint32_t)(i * 2 + 2) ^ 0x9e3779b9U);
        float u1 = ((float)h1 + 1.0f) * (1.0f / 4294967808.0f);
        float u2 = (float)h2 * (1.0f / 4294967296.0f);
        float g = sqrtf(-2.f * logf(u1)) * cosf(6.28318530718f * u2);
        wv[i] = g;
        ssq += g * g;
    }
    float tot = blockReduceSum256(ssq);
    if (t == 0) part[b] = tot;
}

// block = a: v = wv/nrm; w1[m,d] = sum_c v[a,m,c]*Gc[c,d]; w2[a,n,d] = sum_m w1[m,d]*Gs[m,n]
__global__ __launch_bounds__(256) void k_pA(const float* __restrict__ wv, const float* __restrict__ part,
                                            const float* __restrict__ Gc, const float* __restrict__ Gs,
                                            float* __restrict__ w2) {
    __shared__ float lv[2048];
    __shared__ float lw1[2048];
    int a = blockIdx.x, t = threadIdx.x;
    float s = (t < 128) ? part[t] : 0.f;
    float tot = blockReduceSum256(s);
    float inv = 1.f / (sqrtf(tot) + 1e-12f);
    for (int e = t; e < 2048; e += 256) lv[e] = wv[a * 2048 + e] * inv;
    __syncthreads();
    if (t < 128) {
        int m = t;
        float vv[16];
        #pragma unroll
        for (int c = 0; c < 16; ++c) vv[c] = lv[m * 16 + c];
        #pragma unroll
        for (int d = 0; d < 16; ++d) {
            float acc = 0.f;
            #pragma unroll
            for (int c = 0; c < 16; ++c) acc = fmaf(vv[c], Gc[c * 16 + d], acc);
            lw1[m * 16 + d] = acc;
        }
    }
    __syncthreads();
    {
        int n = t >> 1, d0 = (t & 1) * 8;
        float acc[8];
        #pragma unroll
        for (int k = 0; k < 8; ++k) acc[k] = 0.f;
        for (int m = 0; m < 128; ++m) {
            float gsv = Gs[m * 128 + n];
            float4 w0 = *(const float4*)&lw1[m * 16 + d0];
            float4 w1v = *(const float4*)&lw1[m * 16 + d0 + 4];
            acc[0] = fmaf(w0.x, gsv, acc[0]); acc[1] = fmaf(w0.y, gsv, acc[1]);
            acc[2] = fmaf(w0.z, gsv, acc[2]); acc[3] = fmaf(w0.w, gsv, acc[3]);
            acc[4] = fmaf(w1v.x, gsv, acc[4]); acc[5] = fmaf(w1v.y, gsv, acc[5]);
            acc[6] = fmaf(w1v.z, gsv, acc[6]); acc[7] = fmaf(w1v.w, gsv, acc[7]);
        }
        float* op = &w2[a * 2048 + n * 16 + d0];
        *(float4*)op = make_float4(acc[0], acc[1], acc[2], acc[3]);
        *(float4*)(op + 4) = make_float4(acc[4], acc[5], acc[6], acc[7]);
    }
}

// block = n: wv[b,n,d] = sum_a w2[a,n,d]*Ga[a,b]; part[n] = sum of squares
__global__ __launch_bounds__(256) void k_pB(const float* __restrict__ w2, const float* __restrict__ Ga,
                                            float* __restrict__ wv, float* __restrict__ part) {
    __shared__ float gal[AD * AD];     // 38.4 KB
    __shared__ float w2n[AD * CD];     // 6.3 KB
    int n = blockIdx.x, t = threadIdx.x;
    for (int e = t; e < AD * AD; e += 256) gal[e] = Ga[e];
    for (int e = t; e < AD * CD; e += 256) {
        int aa = e >> 4, d = e & 15;
        w2n[e] = w2[aa * 2048 + n * 16 + d];
    }
    __syncthreads();
    float ssq = 0.f;
    for (int e = t; e < AD * CD; e += 256) {
        int b = e >> 4, d = e & 15;
        float acc = 0.f;
        for (int aa = 0; aa < 98; ++aa) acc = fmaf(w2n[aa * 16 + d], gal[aa * 98 + b], acc);
        wv[b * 2048 + n * 16 + d] = acc;
        ssq += acc * acc;
    }
    float tot = blockReduceSum256(ssq);
    if (t == 0) part[n] = tot;
}

__global__ __launch_bounds__(256) void k_L(const float* __restrict__ part, float* __restrict__ scal) {
    int t = threadIdx.x;
    float s = (t < 128) ? part[t] : 0.f;
    float tot = blockReduceSum256(s);
    if (t == 0) {
        float L = fmaxf(sqrtf(tot), 1e-6f);
        scal[1] = 1.f / L;      // step
        scal[2] = 0.1f / L;     // thr = COUPLE/L
    }
}

// ---------------- FISTA kernels ----------------
// t2 layout h-major: t2[p][h*64 + st], bf16.

// j=1: t2 = xan
__global__ __launch_bounds__(256) void k_copy(const u16* __restrict__ src, u16* __restrict__ dst) {
    size_t i = (size_t)blockIdx.x * 256 + threadIdx.x;
    ((uint4*)dst)[i] = ((const uint4*)src)[i];
}

// t2_new[bn,a,e] = sum_a' Ga[a,a'] * t2[bn,a',e] + xan[bn,a,e]   (in-place per (bn,e-chunk))
__global__ __launch_bounds__(256) void k_gemmA(u16* t2g, const float* __restrict__ Ga,
                                               const u16* __restrict__ xan) {
    __shared__ float lt[98 * 130];     // 51.0 KB
    int ec = blockIdx.x, bn = blockIdx.y, t = threadIdx.x;
    int base = ec * 128;
    for (int e8 = t; e8 < 98 * 16; e8 += 256) {
        int a = e8 >> 4, r8 = e8 & 15;
        uint4 v = *(const uint4*)&t2g[(size_t)(bn * 98 + a) * 512 + base + r8 * 8];
        float* d = &lt[a * 130 + r8 * 8];
        d[0] = bflo(v.x); d[1] = bfhi(v.x); d[2] = bflo(v.y); d[3] = bfhi(v.y);
        d[4] = bflo(v.z); d[5] = bfhi(v.z); d[6] = bflo(v.w); d[7] = bfhi(v.w);
    }
    __syncthreads();
    // 14 a-groups (7 a's each) x 64 e-pairs = 896 tasks; wave-uniform a-group
    for (int tk = t; tk < 896; tk += 256) {
        int g = tk >> 6, i2 = (tk & 63) * 2;
        int a0 = g * 7;
        float acc0[7], acc1[7];
        #pragma unroll
        for (int q = 0; q < 7; ++q) { acc0[q] = 0.f; acc1[q] = 0.f; }
        for (int ap = 0; ap < 98; ++ap) {
            float2 vv = *(const float2*)&lt[ap * 130 + i2];
            #pragma unroll
            for (int q = 0; q < 7; ++q) {
                float w = Ga[(a0 + q) * 98 + ap];   // wave-uniform -> s_load
                acc0[q] = fmaf(vv.x, w, acc0[q]);
                acc1[q] = fmaf(vv.y, w, acc1[q]);
            }
        }
        #pragma unroll
        for (int q = 0; q < 7; ++q) {
            size_t idx = (size_t)(bn * 98 + a0 + q) * 512 + base + i2;
            uint32_t xv = *(const uint32_t*)&xan[idx];
            *(uint32_t*)&t2g[idx] = packbf(acc0[q] + bflo(xv), acc1[q] + bfhi(xv));
        }
    }
}

// MFMA-fused adj_s + dc^T + FISTA + dc + recon_s. Block = 4 waves x 2 slices = 8 slices.
__global__ __launch_bounds__(256) void k_fused(u16* t2g,
                                               const u16* __restrict__ dsAg, const u16* __restrict__ dsCg,
                                               const float* __restrict__ dcg, const float* __restrict__ scal,
                                               const u16* __restrict__ zc, u16* __restrict__ zp,
                                               float betaPrev, float beta, int first, int last) {
    __shared__ float l_t1b[8448];      // [slice(8)][h(8)] rows stride 132 fp32, 33 KB
    __shared__ short l_o[8704];        // [slice(8)][h(8)] rows stride 136 bf16, 17 KB
    int t = threadIdx.x, w = t >> 6, L = t & 63;
    int quad = L >> 4, n = L & 15, s_n = n >> 3, h_n = n & 7;
    int P0 = blockIdx.x * 8 + w * 2;

    // pre-issue global loads: B-frags (stage A) + z streams
    bf16x8 Bf[2];
    #pragma unroll
    for (int kc = 0; kc < 2; ++kc)
        Bf[kc] = *(const bf16x8*)&t2g[(size_t)(P0 + s_n) * 512 + h_n * 64 + kc * 32 + quad * 8];
    uint4 zcr[8], zpr[8];
    bool haveZp = (!first) && (betaPrev != 0.0f);
    if (!first) {
        #pragma unroll
        for (int sl = 0; sl < 2; ++sl)
            #pragma unroll
            for (int mh = 0; mh < 2; ++mh) {
                size_t q = (size_t)(P0 + sl) * 2048 + (size_t)(mh * 64 + L) * 16;
                zcr[(sl * 2 + mh) * 2]     = *(const uint4*)&zc[q];
                zcr[(sl * 2 + mh) * 2 + 1] = *(const uint4*)&zc[q + 8];
            }
    }
    if (haveZp) {
        #pragma unroll
        for (int sl = 0; sl < 2; ++sl)
            #pragma unroll
            for (int mh = 0; mh < 2; ++mh) {
                size_t q = (size_t)(P0 + sl) * 2048 + (size_t)(mh * 64 + L) * 16;
                zpr[(sl * 2 + mh) * 2]     = *(const uint4*)&zp[q];
                zpr[(sl * 2 + mh) * 2 + 1] = *(const uint4*)&zp[q + 8];
            }
    }

    // ---- stage A (MFMA): A-frags from global (L1-hot) ----
    f32x4 accA[8];
    #pragma unroll
    for (int mt = 0; mt < 8; ++mt) accA[mt] = (f32x4){0.f, 0.f, 0.f, 0.f};
    #pragma unroll
    for (int kc = 0; kc < 2; ++kc) {
        #pragma unroll
        for (int mt = 0; mt < 8; ++mt) {
            bf16x8 A = *(const bf16x8*)&dsAg[(mt * 2 + kc) * 512 + L * 8];
            accA[mt] = __builtin_amdgcn_mfma_f32_16x16x32_bf16(A, Bf[kc], accA[mt], 0, 0, 0);
        }
    }
    {
        int col = ((w * 2 + s_n) * 8 + h_n) * 132;
        #pragma unroll
        for (int mt = 0; mt < 8; ++mt)
            *(f32x4*)&l_t1b[col + mt * 16 + quad * 4] = accA[mt];
    }
    __syncthreads();

    // ---- stage B (VALU pointwise FISTA), thread = m ----
    float step = scal[1], thr = scal[2];
    #pragma unroll
    for (int sl = 0; sl < 2; ++sl) {
        int slK = w * 2 + sl;
        #pragma unroll
        for (int mh = 0; mh < 2; ++mh) {
            int m = mh * 64 + L, ri = sl * 2 + mh;
            float tb[8];
            #pragma unroll
            for (int h = 0; h < 8; ++h) tb[h] = l_t1b[(slK * 8 + h) * 132 + m];
            float g[16];
            #pragma unroll
            for (int c = 0; c < 16; ++c) {
                float s = 0.f;
                #pragma unroll
                for (int h = 0; h < 8; ++h) s = fmaf(tb[h], dcg[c * 8 + h], s);
                g[c] = s;
            }
            float zcv[16], zpv[16];
            #pragma unroll
            for (int c = 0; c < 16; ++c) { zcv[c] = 0.f; zpv[c] = 0.f; }
            if (!first) {
                uint4 a0 = zcr[ri * 2], a1 = zcr[ri * 2 + 1];
                zcv[0] = bflo(a0.x); zcv[1] = bfhi(a0.x); zcv[2] = bflo(a0.y); zcv[3] = bfhi(a0.y);
                zcv[4] = bflo(a0.z); zcv[5] = bfhi(a0.z); zcv[6] = bflo(a0.w); zcv[7] = bfhi(a0.w);
                zcv[8] = bflo(a1.x); zcv[9] = bfhi(a1.x); zcv[10] = bflo(a1.y); zcv[11] = bfhi(a1.y);
                zcv[12] = bflo(a1.z); zcv[13] = bfhi(a1.z); zcv[14] = bflo(a1.w); zcv[15] = bfhi(a1.w);
            }
            if (haveZp) {
                uint4 b0 = zpr[ri * 2], b1 = zpr[ri * 2 + 1];
                zpv[0] = bflo(b0.x); zpv[1] = bfhi(b0.x); zpv[2] = bflo(b0.y); zpv[3] = bfhi(b0.y);
                zpv[4] = bflo(b0.z); zpv[5] = bfhi(b0.z); zpv[6] = bflo(b0.w); zpv[7] = bfhi(b0.w);
                zpv[8] = bflo(b1.x); zpv[9] = bfhi(b1.x); zpv[10] = bflo(b1.y); zpv[11] = bfhi(b1.y);
                zpv[12] = bflo(b1.z); zpv[13] = bfhi(b1.z); zpv[14] = bflo(b1.w); zpv[15] = bfhi(b1.w);
            }
            float zn[16], src[16];
            #pragma unroll
            for (int c = 0; c < 16; ++c) {
                float y  = fmaf(betaPrev, zcv[c] - zpv[c], zcv[c]);
                float pv = fmaf(-step, g[c], y);
                float av = fabsf(pv) - thr;
                float z1 = (av > 0.f) ? copysignf(av, pv) : 0.f;
                zn[c] = z1;
                src[c] = last ? z1 : fmaf(beta, z1 - zcv[c], z1);
            }
            if (!last) {
                size_t q = (size_t)(P0 + sl) * 2048 + (size_t)m * 16;
                uint4 o0, o1;
                o0.x = packbf(zn[0], zn[1]);  o0.y = packbf(zn[2], zn[3]);
                o0.z = packbf(zn[4], zn[5]);  o0.w = packbf(zn[6], zn[7]);
                o1.x = packbf(zn[8], zn[9]);  o1.y = packbf(zn[10], zn[11]);
                o1.z = packbf(zn[12], zn[13]); o1.w = packbf(zn[14], zn[15]);
                *(uint4*)&zp[q] = o0;
                *(uint4*)&zp[q + 8] = o1;
            }
            #pragma unroll
            for (int h = 0; h < 8; ++h) {
                float s = 0.f;
                #pragma unroll
                for (int c = 0; c < 16; ++c) s = fmaf(src[c], dcg[c * 8 + h], s);
                l_o[(slK * 8 + h) * 136 + m] = (short)bf1(s);
            }
        }
    }
    __syncthreads();

    // ---- stage C (MFMA): A2-frags from global ----
    f32x4 accC[4];
    #pragma unroll
    for (int mt2 = 0; mt2 < 4; ++mt2) accC[mt2] = (f32x4){0.f, 0.f, 0.f, 0.f};
    #pragma unroll
    for (int kc = 0; kc < 4; ++kc) {
        bf16x8 B2 = *(const bf16x8*)&l_o[((w * 2 + s_n) * 8 + h_n) * 136 + kc * 32 + quad * 8];
        #pragma unroll
        for (int mt2 = 0; mt2 < 4; ++mt2) {
            bf16x8 A2 = *(const bf16x8*)&dsCg[(mt2 * 4 + kc) * 512 + L * 8];
            accC[mt2] = __builtin_amdgcn_mfma_f32_16x16x32_bf16(A2, B2, accC[mt2], 0, 0, 0);
        }
    }
    #pragma unroll
    for (int mt2 = 0; mt2 < 4; ++mt2) {
        uint2 ov = make_uint2(packbf(accC[mt2][0], accC[mt2][1]),
                              packbf(accC[mt2][2], accC[mt2][3]));
        *(uint2*)&t2g[(size_t)(P0 + s_n) * 512 + h_n * 64 + mt2 * 16 + quad * 4] = ov;
    }
}

// Final angular recon from h-major t2 -> st-major fp32 out
__global__ __launch_bounds__(128) void k_recon_out(const u16* __restrict__ t2, const float* __restrict__ da,
                                                   float* __restrict__ out) {
    __shared__ float lt2[16 * 512];
    __shared__ float l_t[7 * 520];
    int uvg = blockIdx.x, bn = blockIdx.y, t = threadIdx.x;
    float4 acc[7];
    #pragma unroll
    for (int u = 0; u < 7; ++u) acc[u] = make_float4(0.f, 0.f, 0.f, 0.f);
    for (int c0 = 0; c0 < AD; c0 += 16) {
        int na = min(16, AD - c0);
        for (int e8 = t; e8 < na * 64; e8 += 128) {
            uint4 v = *(const uint4*)&t2[(size_t)(bn * AD + c0) * 512 + e8 * 8];
            float* d = &lt2[e8 * 8];
            d[0] = bflo(v.x); d[1] = bfhi(v.x); d[2] = bflo(v.y); d[3] = bfhi(v.y);
            d[4] = bflo(v.z); d[5] = bfhi(v.z); d[6] = bflo(v.w); d[7] = bfhi(v.w);
        }
        __syncthreads();
        for (int al = 0; al < na; ++al) {
            float4 rv = *(const float4*)&lt2[al * 512 + t * 4];
            int a = c0 + al;
            #pragma unroll
            for (int u = 0; u < 7; ++u)
                fma4(acc[u], rv, da[a * 49 + uvg * 7 + u]);
        }
        __syncthreads();
    }
    #pragma unroll
    for (int u = 0; u < 7; ++u)
        *(float4*)&l_t[u * 520 + t * 4] = acc[u];
    __syncthreads();
    for (int f = t; f < 896; f += 128) {
        int u = f >> 7, e4 = (f & 127) * 4;
        int st = e4 >> 3, h0 = e4 & 7;
        float4 o;
        o.x = l_t[u * 520 + (h0 + 0) * 64 + st];
        o.y = l_t[u * 520 + (h0 + 1) * 64 + st];
        o.z = l_t[u * 520 + (h0 + 2) * 64 + st];
        o.w = l_t[u * 520 + (h0 + 3) * 64 + st];
        *(float4*)&out[(size_t)bn * 25088 + (size_t)(uvg * 7 + u) * 512 + e4] = o;
    }
}

// ---------------- launcher ----------------

extern "C" void kernel_launch(void* const* d_in, const int* in_sizes, int n_in,
                              void* d_out, int out_size, void* d_ws, size_t ws_size,
                              hipStream_t stream) {
    const float* x  = (const float*)d_in[0];
    const float* da = (const float*)d_in[1];
    const float* ds = (const float*)d_in[2];
    const float* dc = (const float*)d_in[3];
    float* out = (float*)d_out;

    char* base = (char*)d_ws;
    u16* Za   = (u16*)base; base += (size_t)ZSZ * 2;    // 102.76 MB
    u16* Zb   = (u16*)base; base += (size_t)ZSZ * 2;    // 102.76 MB
    u16* t2   = (u16*)base; base += (size_t)T2SZ * 2;   // 25.69 MB
    u16* xan  = (u16*)base; base += (size_t)T2SZ * 2;   // 25.69 MB
    u16* dsAg = (u16*)base; base += 8192 * 2;
    u16* dsCg = (u16*)base; base += 8192 * 2;
    float* fb = (float*)base;
    size_t off = 0;
    float* Ga   = fb + off; off += 9604;
    float* Gs   = fb + off; off += 16384;
    float* Gc   = fb + off; off += 256;
    float* w2   = fb + off; off += PVSZ;
    float* wv   = fb + off; off += PVSZ;
    float* part = fb + off; off += 128;
    float* scal = fb + off; off += 4;
    (void)ws_size; (void)in_sizes; (void)n_in; (void)out_size;

    // ---- prep + xan + power iteration ----
    k_prep<<<167, 256, 0, stream>>>(da, ds, dc, dsAg, dsCg, Ga, Gs, Gc);
    k_xa<<<dim3(8, 256), 256, 0, stream>>>(x, da, xan);
    k_v0<<<128, 256, 0, stream>>>(wv, part);
    for (int it = 0; it < 10; ++it) {
        k_pA<<<98, 256, 0, stream>>>(wv, part, Gc, Gs, w2);
        k_pB<<<128, 256, 0, stream>>>(w2, Ga, wv, part);
    }
    k_L<<<1, 256, 0, stream>>>(part, scal);

    // ---- beta schedule ----
    float betaArr[16];
    betaArr[0] = 0.f;
    double tprev = 1.0;
    for (int j = 1; j <= 15; ++j) {
        double tn = (1.0 + sqrt(1.0 + 4.0 * tprev * tprev)) * 0.5;
        betaArr[j] = (float)((tprev - 1.0) / tn);
        tprev = tn;
    }

    // ---- FISTA: 15 iterations ----
    u16* zbufs[2] = { Za, Zb };
    for (int j = 1; j <= 15; ++j) {
        if (j == 1) {
            k_copy<<<T2SZ / (256 * 8), 256, 0, stream>>>(xan, t2);
        } else {
            k_gemmA<<<dim3(4, 256), 256, 0, stream>>>(t2, Ga, xan);
        }
        const u16* zc = zbufs[1 - (j & 1)];   // z_{j-1}
        u16* zp = zbufs[j & 1];               // z_{j-2} -> becomes z_j
        k_fused<<<3136, 256, 0, stream>>>(t2, dsAg, dsCg, dc, scal, zc, zp,
                                          (j >= 2) ? betaArr[j - 1] : 0.f, betaArr[j],
                                          (j == 1) ? 1 : 0, (j == 15) ? 1 : 0);
    }

    // ---- final recon(z15) -> out ----
    k_recon_out<<<dim3(7, 256), 128, 0, stream>>>(t2, da, out);
}

// Round 10
// 2287.748 us; speedup vs baseline: 1.9242x; 1.9242x over previous
//
#include <hip/hip_runtime.h>
#include <math.h>
#include <stdint.h>

// Dims
#define BN    256      // B*N
#define UVD   49       // U*V
#define STD_  64       // S*T
#define CHD   8
#define AD    98
#define MD    128
#define CD    16

#define ZSZ   (BN*AD*MD*CD)      // 51,380,224 elements
#define T2SZ  (BN*AD*STD_*CHD)   // 12,845,056
#define PVSZ  (AD*MD*CD)         // 200,704

typedef unsigned short u16;
typedef __attribute__((ext_vector_type(8))) short bf16x8;
typedef __attribute__((ext_vector_type(4))) float f32x4;

// ---- bf16 helpers (internal storage bf16, compute fp32) ----
__device__ __forceinline__ float bflo(uint32_t u) {
    return __builtin_bit_cast(float, u << 16);
}
__device__ __forceinline__ float bfhi(uint32_t u) {
    return __builtin_bit_cast(float, u & 0xFFFF0000u);
}
__device__ __forceinline__ uint32_t packbf(float lo, float hi) {  // RNE pack 2 fp32 -> 2 bf16
    uint32_t a = __builtin_bit_cast(uint32_t, lo);
    uint32_t b = __builtin_bit_cast(uint32_t, hi);
    a = (a + 0x7FFFu + ((a >> 16) & 1u)) >> 16;
    b = (b + 0x7FFFu + ((b >> 16) & 1u)) >> 16;
    return a | (b << 16);
}
__device__ __forceinline__ u16 bf1(float f) {   // RNE fp32 -> bf16
    uint32_t a = __builtin_bit_cast(uint32_t, f);
    a = (a + 0x7FFFu + ((a >> 16) & 1u)) >> 16;
    return (u16)a;
}

__device__ __forceinline__ void fma4(float4& a, const float4& v, float s) {
    a.x = fmaf(v.x, s, a.x); a.y = fmaf(v.y, s, a.y);
    a.z = fmaf(v.z, s, a.z); a.w = fmaf(v.w, s, a.w);
}

__device__ __forceinline__ uint32_t hsh(uint32_t x) {
    x ^= x >> 16; x *= 0x7feb352dU;
    x ^= x >> 15; x *= 0x846ca68bU;
    x ^= x >> 16; return x;
}

__device__ __forceinline__ float blockReduceSum256(float s) {
    __shared__ float sw[4];
    #pragma unroll
    for (int o = 32; o > 0; o >>= 1) s += __shfl_down(s, o, 64);
    int lane = threadIdx.x & 63, wi = threadIdx.x >> 6;
    if (lane == 0) sw[wi] = s;
    __syncthreads();
    return sw[0] + sw[1] + sw[2] + sw[3];
}

// ---------------- prep: fragment-ordered ds/Ga (bf16) + Gram matrices ----------------

__global__ __launch_bounds__(256) void k_prep(const float* __restrict__ da, const float* __restrict__ ds,
                                              const float* __restrict__ dc,
                                              u16* __restrict__ dsAg, u16* __restrict__ dsCg,
                                              u16* __restrict__ GaBF,
                                              float* __restrict__ Ga, float* __restrict__ Gs,
                                              float* __restrict__ Gc) {
    int i = blockIdx.x * 256 + threadIdx.x;
    if (i < 8192) {                        // stage-A frags: A[m][k=st]
        int f = i >> 9, r = i & 511, L = r >> 3, j = r & 7;
        int mt = f >> 1, kc = f & 1;
        int m = mt * 16 + (L & 15), st = kc * 32 + (L >> 4) * 8 + j;
        dsAg[i] = bf1(ds[m * 64 + st]);
        return;
    }
    int i2 = i - 8192;
    if (i2 < 8192) {                       // stage-C frags: A2[st][k=m]
        int f = i2 >> 9, r = i2 & 511, L = r >> 3, j = r & 7;
        int mt2 = f >> 2, kc = f & 3;
        int st = mt2 * 16 + (L & 15), m = kc * 32 + (L >> 4) * 8 + j;
        dsCg[i2] = bf1(ds[m * 64 + st]);
        return;
    }
    int jg = i2 - 8192;
    if (jg < 9604) {                       // Ga 98x98 (symmetric) fp32
        int a = jg / 98, b = jg % 98;
        float s = 0.f;
        for (int uv = 0; uv < 49; ++uv) s = fmaf(da[a * 49 + uv], da[b * 49 + uv], s);
        Ga[jg] = s;
        return;
    }
    int k = jg - 9604;
    if (k < 16384) {                       // Gs 128x128
        int m = k >> 7, n = k & 127;
        float s = 0.f;
        for (int st = 0; st < 64; ++st) s = fmaf(ds[m * 64 + st], ds[n * 64 + st], s);
        Gs[k] = s;
        return;
    }
    int l = k - 16384;
    if (l < 256) {                         // Gc 16x16
        int c = l >> 4, d = l & 15;
        float s = 0.f;
        for (int h = 0; h < 8; ++h) s = fmaf(dc[c * 8 + h], dc[d * 8 + h], s);
        Gc[l] = s;
        return;
    }
    int gb = l - 256;
    if (gb < 16384) {                      // GaBF: B[k=a'][n=a] frags, 32 frags (nt 0..7, kc 0..3)
        int f = gb >> 9, r = gb & 511, L = r >> 3, j = r & 7;
        int nt = f >> 2, kc = f & 3;
        int a = nt * 16 + (L & 15), ap = kc * 32 + (L >> 4) * 8 + j;
        float v = 0.f;
        if (a < 98 && ap < 98) {
            float s = 0.f;
            for (int uv = 0; uv < 49; ++uv) s = fmaf(da[ap * 49 + uv], da[a * 49 + uv], s);
            v = s;
        }
        GaBF[gb] = bf1(v);
    }
}

// ---------------- one-time: xan = -adj_a(x), h-major bf16 ----------------

__global__ __launch_bounds__(256) void k_xa(const float* __restrict__ xg, const float* __restrict__ da,
                                            u16* __restrict__ xan) {
    __shared__ float l_r[49 * 68];     // 13.0 KB
    int ch = blockIdx.x, bn = blockIdx.y, t = threadIdx.x;   // ch = h (0..7)
    int base = ch * 64;
    size_t xbase = (size_t)bn * 25088;
    for (int e2 = t; e2 < 1568; e2 += 256) {
        int uv = e2 >> 5, i2 = (e2 & 31) * 2;
        float x0 = xg[xbase + uv * 512 + i2 * 8 + ch];
        float x1 = xg[xbase + uv * 512 + (i2 + 1) * 8 + ch];
        l_r[uv * 68 + i2]     = -x0;
        l_r[uv * 68 + i2 + 1] = -x1;
    }
    __syncthreads();
    for (int e2 = t; e2 < 3136; e2 += 256) {
        int a = e2 >> 5, i2 = (e2 & 31) * 2;
        float s0 = 0.f, s1 = 0.f;
        for (int uv = 0; uv < 49; ++uv) {
            float w = da[a * 49 + uv];
            s0 = fmaf(l_r[uv * 68 + i2], w, s0);
            s1 = fmaf(l_r[uv * 68 + i2 + 1], w, s1);
        }
        *(uint32_t*)&xan[(size_t)(bn * 98 + a) * 512 + base + i2] = packbf(s0, s1);
    }
}

// ---------------- joint 10-iter power iteration (fused, lazy-normalized) ----------------

__global__ __launch_bounds__(256) void k_v0(float* __restrict__ wv, float* __restrict__ part) {
    int b = blockIdx.x, t = threadIdx.x;
    float ssq = 0.f;
    for (int i = b * 1568 + t; i < (b + 1) * 1568; i += 256) {
        uint32_t h1 = hsh((uint32_t)(i * 2 + 1));
        uint32_t h2 = hsh((uint32_t)(i * 2 + 2) ^ 0x9e3779b9U);
        float u1 = ((float)h1 + 1.0f) * (1.0f / 4294967808.0f);
        float u2 = (float)h2 * (1.0f / 4294967296.0f);
        float g = sqrtf(-2.f * logf(u1)) * cosf(6.28318530718f * u2);
        wv[i] = g;
        ssq += g * g;
    }
    float tot = blockReduceSum256(ssq);
    if (t == 0) part[b] = tot;
}

__global__ __launch_bounds__(256) void k_pA(const float* __restrict__ wv, const float* __restrict__ part,
                                            const float* __restrict__ Gc, const float* __restrict__ Gs,
                                            float* __restrict__ w2) {
    __shared__ float lv[2048];
    __shared__ float lw1[2048];
    int a = blockIdx.x, t = threadIdx.x;
    float s = (t < 128) ? part[t] : 0.f;
    float tot = blockReduceSum256(s);
    float inv = 1.f / (sqrtf(tot) + 1e-12f);
    for (int e = t; e < 2048; e += 256) lv[e] = wv[a * 2048 + e] * inv;
    __syncthreads();
    if (t < 128) {
        int m = t;
        float vv[16];
        #pragma unroll
        for (int c = 0; c < 16; ++c) vv[c] = lv[m * 16 + c];
        #pragma unroll
        for (int d = 0; d < 16; ++d) {
            float acc = 0.f;
            #pragma unroll
            for (int c = 0; c < 16; ++c) acc = fmaf(vv[c], Gc[c * 16 + d], acc);
            lw1[m * 16 + d] = acc;
        }
    }
    __syncthreads();
    {
        int n = t >> 1, d0 = (t & 1) * 8;
        float acc[8];
        #pragma unroll
        for (int k = 0; k < 8; ++k) acc[k] = 0.f;
        for (int m = 0; m < 128; ++m) {
            float gsv = Gs[m * 128 + n];
            float4 w0 = *(const float4*)&lw1[m * 16 + d0];
            float4 w1v = *(const float4*)&lw1[m * 16 + d0 + 4];
            acc[0] = fmaf(w0.x, gsv, acc[0]); acc[1] = fmaf(w0.y, gsv, acc[1]);
            acc[2] = fmaf(w0.z, gsv, acc[2]); acc[3] = fmaf(w0.w, gsv, acc[3]);
            acc[4] = fmaf(w1v.x, gsv, acc[4]); acc[5] = fmaf(w1v.y, gsv, acc[5]);
            acc[6] = fmaf(w1v.z, gsv, acc[6]); acc[7] = fmaf(w1v.w, gsv, acc[7]);
        }
        float* op = &w2[a * 2048 + n * 16 + d0];
        *(float4*)op = make_float4(acc[0], acc[1], acc[2], acc[3]);
        *(float4*)(op + 4) = make_float4(acc[4], acc[5], acc[6], acc[7]);
    }
}

__global__ __launch_bounds__(256) void k_pB(const float* __restrict__ w2, const float* __restrict__ Ga,
                                            float* __restrict__ wv, float* __restrict__ part) {
    __shared__ float gal[AD * AD];     // 38.4 KB
    __shared__ float w2n[AD * CD];     // 6.3 KB
    int n = blockIdx.x, t = threadIdx.x;
    for (int e = t; e < AD * AD; e += 256) gal[e] = Ga[e];
    for (int e = t; e < AD * CD; e += 256) {
        int aa = e >> 4, d = e & 15;
        w2n[e] = w2[aa * 2048 + n * 16 + d];
    }
    __syncthreads();
    float ssq = 0.f;
    for (int e = t; e < AD * CD; e += 256) {
        int b = e >> 4, d = e & 15;
        float acc = 0.f;
        for (int aa = 0; aa < 98; ++aa) acc = fmaf(w2n[aa * 16 + d], gal[aa * 98 + b], acc);
        wv[b * 2048 + n * 16 + d] = acc;
        ssq += acc * acc;
    }
    float tot = blockReduceSum256(ssq);
    if (t == 0) part[n] = tot;
}

__global__ __launch_bounds__(256) void k_L(const float* __restrict__ part, float* __restrict__ scal) {
    int t = threadIdx.x;
    float s = (t < 128) ? part[t] : 0.f;
    float tot = blockReduceSum256(s);
    if (t == 0) {
        float L = fmaxf(sqrtf(tot), 1e-6f);
        scal[1] = 1.f / L;      // step
        scal[2] = 0.1f / L;     // thr = COUPLE/L
    }
}

// ---------------- FISTA kernels ----------------
// t2 layout h-major: t2[p][h*64 + st], bf16.

// j=1: t2 = xan
__global__ __launch_bounds__(256) void k_copy(const u16* __restrict__ src, u16* __restrict__ dst) {
    size_t i = (size_t)blockIdx.x * 256 + threadIdx.x;
    ((uint4*)dst)[i] = ((const uint4*)src)[i];
}

// MFMA angular: t2_new[bn,a,e] = sum_a' Ga[a,a']*t2[bn,a',e] + xan[bn,a,e], per (e-chunk 128, bn).
// Computed as C[m=e][n=a] = sum_k ltT[e][k=a'] * GaBF[k=a'][n=a] (Ga symmetric).
__global__ __launch_bounds__(256) void k_angA(u16* t2g, const u16* __restrict__ GaBF,
                                              const u16* __restrict__ xan) {
    __shared__ short ltT[128 * 136];   // 34.8 KB, e-rows, stride 136 (2-way bank aliasing = free)
    int ec = blockIdx.x, bn = blockIdx.y, t = threadIdx.x;
    int w = t >> 6, L = t & 63, quad = L >> 4, n = L & 15;
    size_t rowbase = (size_t)bn * 98 * 512 + ec * 128;

    // stage: load t2 chunk (98 a' x 128 e), transpose into ltT[e][a']
    for (int i = t; i < 1568; i += 256) {
        int ap = i >> 4, e8 = (i & 15) * 8;
        uint4 v = *(const uint4*)&t2g[rowbase + (size_t)ap * 512 + e8];
        u16 e0 = (u16)(v.x & 0xFFFF), e1 = (u16)(v.x >> 16);
        u16 e2 = (u16)(v.y & 0xFFFF), e3 = (u16)(v.y >> 16);
        u16 e4 = (u16)(v.z & 0xFFFF), e5 = (u16)(v.z >> 16);
        u16 e6 = (u16)(v.w & 0xFFFF), e7 = (u16)(v.w >> 16);
        ltT[(e8 + 0) * 136 + ap] = e0; ltT[(e8 + 1) * 136 + ap] = e1;
        ltT[(e8 + 2) * 136 + ap] = e2; ltT[(e8 + 3) * 136 + ap] = e3;
        ltT[(e8 + 4) * 136 + ap] = e4; ltT[(e8 + 5) * 136 + ap] = e5;
        ltT[(e8 + 6) * 136 + ap] = e6; ltT[(e8 + 7) * 136 + ap] = e7;
    }
    // CRITICAL: zero the K-padding columns a' = 98..129 (A-frags read k up to 127;
    // uninitialized LDS here decodes to NaN ~1.6% of the time and NaN*0 = NaN,
    // which the prox step then flushes to z=0 -> silent all-zero output).
    for (int i = t; i < 128 * 32; i += 256) {
        int e = i >> 5, c = 98 + (i & 31);
        ltT[e * 136 + c] = 0;
    }
    __syncthreads();

    // MFMA: wave w handles n-tiles nt0 = 2w, nt1 = 2w+1 (nt=7 hits only a>=98: dropped on store)
    int nt0 = w * 2, nt1 = w * 2 + 1;
    f32x4 acc0[8], acc1[8];
    #pragma unroll
    for (int mt = 0; mt < 8; ++mt) { acc0[mt] = (f32x4){0,0,0,0}; acc1[mt] = (f32x4){0,0,0,0}; }
    #pragma unroll
    for (int kc = 0; kc < 4; ++kc) {
        bf16x8 B0 = *(const bf16x8*)&GaBF[(nt0 * 4 + kc) * 512 + L * 8];
        bf16x8 B1 = *(const bf16x8*)&GaBF[(nt1 * 4 + kc) * 512 + L * 8];
        #pragma unroll
        for (int mt = 0; mt < 8; ++mt) {
            bf16x8 A = *(const bf16x8*)&ltT[(mt * 16 + n) * 136 + kc * 32 + quad * 8];
            acc0[mt] = __builtin_amdgcn_mfma_f32_16x16x32_bf16(A, B0, acc0[mt], 0, 0, 0);
            acc1[mt] = __builtin_amdgcn_mfma_f32_16x16x32_bf16(A, B1, acc1[mt], 0, 0, 0);
        }
    }

    // epilogue: += xan, pack, store.  C row = e = mt*16 + quad*4 + r, col = a = nt*16 + n.
    #pragma unroll
    for (int half = 0; half < 2; ++half) {
        int a = (half ? nt1 : nt0) * 16 + n;
        if (a < 98) {
            #pragma unroll
            for (int mt = 0; mt < 8; ++mt) {
                f32x4 acc = half ? acc1[mt] : acc0[mt];
                size_t idx = rowbase + (size_t)a * 512 + mt * 16 + quad * 4;
                uint2 xv = *(const uint2*)&xan[idx];
                float v0 = acc[0] + bflo(xv.x), v1 = acc[1] + bfhi(xv.x);
                float v2 = acc[2] + bflo(xv.y), v3 = acc[3] + bfhi(xv.y);
                *(uint2*)&t2g[idx] = make_uint2(packbf(v0, v1), packbf(v2, v3));
            }
        }
    }
}

// MFMA-fused adj_s + dc^T + FISTA + dc + recon_s. Block = 4 waves x 2 slices = 8 slices.
__global__ __launch_bounds__(256) void k_fused(u16* t2g,
                                               const u16* __restrict__ dsAg, const u16* __restrict__ dsCg,
                                               const float* __restrict__ dcg, const float* __restrict__ scal,
                                               const u16* __restrict__ zc, u16* __restrict__ zp,
                                               float betaPrev, float beta, int first, int last) {
    __shared__ float l_t1b[8448];      // [slice(8)][h(8)] rows stride 132 fp32, 33 KB
    __shared__ short l_o[8704];        // [slice(8)][h(8)] rows stride 136 bf16, 17 KB
    int t = threadIdx.x, w = t >> 6, L = t & 63;
    int quad = L >> 4, n = L & 15, s_n = n >> 3, h_n = n & 7;
    int P0 = blockIdx.x * 8 + w * 2;

    // pre-issue global loads: B-frags (stage A) + z streams
    bf16x8 Bf[2];
    #pragma unroll
    for (int kc = 0; kc < 2; ++kc)
        Bf[kc] = *(const bf16x8*)&t2g[(size_t)(P0 + s_n) * 512 + h_n * 64 + kc * 32 + quad * 8];
    uint4 zcr[8], zpr[8];
    bool haveZp = (!first) && (betaPrev != 0.0f);
    if (!first) {
        #pragma unroll
        for (int sl = 0; sl < 2; ++sl)
            #pragma unroll
            for (int mh = 0; mh < 2; ++mh) {
                size_t q = (size_t)(P0 + sl) * 2048 + (size_t)(mh * 64 + L) * 16;
                zcr[(sl * 2 + mh) * 2]     = *(const uint4*)&zc[q];
                zcr[(sl * 2 + mh) * 2 + 1] = *(const uint4*)&zc[q + 8];
            }
    }
    if (haveZp) {
        #pragma unroll
        for (int sl = 0; sl < 2; ++sl)
            #pragma unroll
            for (int mh = 0; mh < 2; ++mh) {
                size_t q = (size_t)(P0 + sl) * 2048 + (size_t)(mh * 64 + L) * 16;
                zpr[(sl * 2 + mh) * 2]     = *(const uint4*)&zp[q];
                zpr[(sl * 2 + mh) * 2 + 1] = *(const uint4*)&zp[q + 8];
            }
    }

    // ---- stage A (MFMA): A-frags from global (L1-hot) ----
    f32x4 accA[8];
    #pragma unroll
    for (int mt = 0; mt < 8; ++mt) accA[mt] = (f32x4){0.f, 0.f, 0.f, 0.f};
    #pragma unroll
    for (int kc = 0; kc < 2; ++kc) {
        #pragma unroll
        for (int mt = 0; mt < 8; ++mt) {
            bf16x8 A = *(const bf16x8*)&dsAg[(mt * 2 + kc) * 512 + L * 8];
            accA[mt] = __builtin_amdgcn_mfma_f32_16x16x32_bf16(A, Bf[kc], accA[mt], 0, 0, 0);
        }
    }
    {
        int col = ((w * 2 + s_n) * 8 + h_n) * 132;
        #pragma unroll
        for (int mt = 0; mt < 8; ++mt)
            *(f32x4*)&l_t1b[col + mt * 16 + quad * 4] = accA[mt];
    }
    __syncthreads();

    // ---- stage B (VALU pointwise FISTA), thread = m ----
    float step = scal[1], thr = scal[2];
    #pragma unroll
    for (int sl = 0; sl < 2; ++sl) {
        int slK = w * 2 + sl;
        #pragma unroll
        for (int mh = 0; mh < 2; ++mh) {
            int m = mh * 64 + L, ri = sl * 2 + mh;
            float tb[8];
            #pragma unroll
            for (int h = 0; h < 8; ++h) tb[h] = l_t1b[(slK * 8 + h) * 132 + m];
            float g[16];
            #pragma unroll
            for (int c = 0; c < 16; ++c) {
                float s = 0.f;
                #pragma unroll
                for (int h = 0; h < 8; ++h) s = fmaf(tb[h], dcg[c * 8 + h], s);
                g[c] = s;
            }
            float zcv[16], zpv[16];
            #pragma unroll
            for (int c = 0; c < 16; ++c) { zcv[c] = 0.f; zpv[c] = 0.f; }
            if (!first) {
                uint4 a0 = zcr[ri * 2], a1 = zcr[ri * 2 + 1];
                zcv[0] = bflo(a0.x); zcv[1] = bfhi(a0.x); zcv[2] = bflo(a0.y); zcv[3] = bfhi(a0.y);
                zcv[4] = bflo(a0.z); zcv[5] = bfhi(a0.z); zcv[6] = bflo(a0.w); zcv[7] = bfhi(a0.w);
                zcv[8] = bflo(a1.x); zcv[9] = bfhi(a1.x); zcv[10] = bflo(a1.y); zcv[11] = bfhi(a1.y);
                zcv[12] = bflo(a1.z); zcv[13] = bfhi(a1.z); zcv[14] = bflo(a1.w); zcv[15] = bfhi(a1.w);
            }
            if (haveZp) {
                uint4 b0 = zpr[ri * 2], b1 = zpr[ri * 2 + 1];
                zpv[0] = bflo(b0.x); zpv[1] = bfhi(b0.x); zpv[2] = bflo(b0.y); zpv[3] = bfhi(b0.y);
                zpv[4] = bflo(b0.z); zpv[5] = bfhi(b0.z); zpv[6] = bflo(b0.w); zpv[7] = bfhi(b0.w);
                zpv[8] = bflo(b1.x); zpv[9] = bfhi(b1.x); zpv[10] = bflo(b1.y); zpv[11] = bfhi(b1.y);
                zpv[12] = bflo(b1.z); zpv[13] = bfhi(b1.z); zpv[14] = bflo(b1.w); zpv[15] = bfhi(b1.w);
            }
            float zn[16], src[16];
            #pragma unroll
            for (int c = 0; c < 16; ++c) {
                float y  = fmaf(betaPrev, zcv[c] - zpv[c], zcv[c]);
                float pv = fmaf(-step, g[c], y);
                float av = fabsf(pv) - thr;
                float z1 = (av > 0.f) ? copysignf(av, pv) : 0.f;
                zn[c] = z1;
                src[c] = last ? z1 : fmaf(beta, z1 - zcv[c], z1);
            }
            if (!last) {
                size_t q = (size_t)(P0 + sl) * 2048 + (size_t)m * 16;
                uint4 o0, o1;
                o0.x = packbf(zn[0], zn[1]);  o0.y = packbf(zn[2], zn[3]);
                o0.z = packbf(zn[4], zn[5]);  o0.w = packbf(zn[6], zn[7]);
                o1.x = packbf(zn[8], zn[9]);  o1.y = packbf(zn[10], zn[11]);
                o1.z = packbf(zn[12], zn[13]); o1.w = packbf(zn[14], zn[15]);
                *(uint4*)&zp[q] = o0;
                *(uint4*)&zp[q + 8] = o1;
            }
            #pragma unroll
            for (int h = 0; h < 8; ++h) {
                float s = 0.f;
                #pragma unroll
                for (int c = 0; c < 16; ++c) s = fmaf(src[c], dcg[c * 8 + h], s);
                l_o[(slK * 8 + h) * 136 + m] = (short)bf1(s);
            }
        }
    }
    __syncthreads();

    // ---- stage C (MFMA): A2-frags from global ----
    f32x4 accC[4];
    #pragma unroll
    for (int mt2 = 0; mt2 < 4; ++mt2) accC[mt2] = (f32x4){0.f, 0.f, 0.f, 0.f};
    #pragma unroll
    for (int kc = 0; kc < 4; ++kc) {
        bf16x8 B2 = *(const bf16x8*)&l_o[((w * 2 + s_n) * 8 + h_n) * 136 + kc * 32 + quad * 8];
        #pragma unroll
        for (int mt2 = 0; mt2 < 4; ++mt2) {
            bf16x8 A2 = *(const bf16x8*)&dsCg[(mt2 * 4 + kc) * 512 + L * 8];
            accC[mt2] = __builtin_amdgcn_mfma_f32_16x16x32_bf16(A2, B2, accC[mt2], 0, 0, 0);
        }
    }
    #pragma unroll
    for (int mt2 = 0; mt2 < 4; ++mt2) {
        uint2 ov = make_uint2(packbf(accC[mt2][0], accC[mt2][1]),
                              packbf(accC[mt2][2], accC[mt2][3]));
        *(uint2*)&t2g[(size_t)(P0 + s_n) * 512 + h_n * 64 + mt2 * 16 + quad * 4] = ov;
    }
}

// Final angular recon from h-major t2 -> st-major fp32 out
__global__ __launch_bounds__(128) void k_recon_out(const u16* __restrict__ t2, const float* __restrict__ da,
                                                   float* __restrict__ out) {
    __shared__ float lt2[16 * 512];
    __shared__ float l_t[7 * 520];
    int uvg = blockIdx.x, bn = blockIdx.y, t = threadIdx.x;
    float4 acc[7];
    #pragma unroll
    for (int u = 0; u < 7; ++u) acc[u] = make_float4(0.f, 0.f, 0.f, 0.f);
    for (int c0 = 0; c0 < AD; c0 += 16) {
        int na = min(16, AD - c0);
        for (int e8 = t; e8 < na * 64; e8 += 128) {
            uint4 v = *(const uint4*)&t2[(size_t)(bn * AD + c0) * 512 + e8 * 8];
            float* d = &lt2[e8 * 8];
            d[0] = bflo(v.x); d[1] = bfhi(v.x); d[2] = bflo(v.y); d[3] = bfhi(v.y);
            d[4] = bflo(v.z); d[5] = bfhi(v.z); d[6] = bflo(v.w); d[7] = bfhi(v.w);
        }
        __syncthreads();
        for (int al = 0; al < na; ++al) {
            float4 rv = *(const float4*)&lt2[al * 512 + t * 4];
            int a = c0 + al;
            #pragma unroll
            for (int u = 0; u < 7; ++u)
                fma4(acc[u], rv, da[a * 49 + uvg * 7 + u]);
        }
        __syncthreads();
    }
    #pragma unroll
    for (int u = 0; u < 7; ++u)
        *(float4*)&l_t[u * 520 + t * 4] = acc[u];
    __syncthreads();
    for (int f = t; f < 896; f += 128) {
        int u = f >> 7, e4 = (f & 127) * 4;
        int st = e4 >> 3, h0 = e4 & 7;
        float4 o;
        o.x = l_t[u * 520 + (h0 + 0) * 64 + st];
        o.y = l_t[u * 520 + (h0 + 1) * 64 + st];
        o.z = l_t[u * 520 + (h0 + 2) * 64 + st];
        o.w = l_t[u * 520 + (h0 + 3) * 64 + st];
        *(float4*)&out[(size_t)bn * 25088 + (size_t)(uvg * 7 + u) * 512 + e4] = o;
    }
}

// ---------------- launcher ----------------

extern "C" void kernel_launch(void* const* d_in, const int* in_sizes, int n_in,
                              void* d_out, int out_size, void* d_ws, size_t ws_size,
                              hipStream_t stream) {
    const float* x  = (const float*)d_in[0];
    const float* da = (const float*)d_in[1];
    const float* ds = (const float*)d_in[2];
    const float* dc = (const float*)d_in[3];
    float* out = (float*)d_out;

    char* base = (char*)d_ws;
    u16* Za   = (u16*)base; base += (size_t)ZSZ * 2;    // 102.76 MB
    u16* Zb   = (u16*)base; base += (size_t)ZSZ * 2;    // 102.76 MB
    u16* t2   = (u16*)base; base += (size_t)T2SZ * 2;   // 25.69 MB
    u16* xan  = (u16*)base; base += (size_t)T2SZ * 2;   // 25.69 MB
    u16* dsAg = (u16*)base; base += 8192 * 2;
    u16* dsCg = (u16*)base; base += 8192 * 2;
    u16* GaBF = (u16*)base; base += 16384 * 2;
    float* fb = (float*)base;
    size_t off = 0;
    float* Ga   = fb + off; off += 9604;
    float* Gs   = fb + off; off += 16384;
    float* Gc   = fb + off; off += 256;
    float* w2   = fb + off; off += PVSZ;
    float* wv   = fb + off; off += PVSZ;
    float* part = fb + off; off += 128;
    float* scal = fb + off; off += 4;
    (void)ws_size; (void)in_sizes; (void)n_in; (void)out_size;

    // ---- prep + xan + power iteration ----
    k_prep<<<231, 256, 0, stream>>>(da, ds, dc, dsAg, dsCg, GaBF, Ga, Gs, Gc);
    k_xa<<<dim3(8, 256), 256, 0, stream>>>(x, da, xan);
    k_v0<<<128, 256, 0, stream>>>(wv, part);
    for (int it = 0; it < 10; ++it) {
        k_pA<<<98, 256, 0, stream>>>(wv, part, Gc, Gs, w2);
        k_pB<<<128, 256, 0, stream>>>(w2, Ga, wv, part);
    }
    k_L<<<1, 256, 0, stream>>>(part, scal);

    // ---- beta schedule ----
    float betaArr[16];
    betaArr[0] = 0.f;
    double tprev = 1.0;
    for (int j = 1; j <= 15; ++j) {
        double tn = (1.0 + sqrt(1.0 + 4.0 * tprev * tprev)) * 0.5;
        betaArr[j] = (float)((tprev - 1.0) / tn);
        tprev = tn;
    }

    // ---- FISTA: 15 iterations ----
    u16* zbufs[2] = { Za, Zb };
    for (int j = 1; j <= 15; ++j) {
        if (j == 1) {
            k_copy<<<T2SZ / (256 * 8), 256, 0, stream>>>(xan, t2);
        } else {
            k_angA<<<dim3(4, 256), 256, 0, stream>>>(t2, GaBF, xan);
        }
        const u16* zc = zbufs[1 - (j & 1)];   // z_{j-1}
        u16* zp = zbufs[j & 1];               // z_{j-2} -> becomes z_j
        k_fused<<<3136, 256, 0, stream>>>(t2, dsAg, dsCg, dc, scal, zc, zp,
                                          (j >= 2) ? betaArr[j - 1] : 0.f, betaArr[j],
                                          (j == 1) ? 1 : 0, (j == 15) ? 1 : 0);
    }

    // ---- final recon(z15) -> out ----
    k_recon_out<<<dim3(7, 256), 128, 0, stream>>>(t2, da, out);
}

// Round 11
// 2076.498 us; speedup vs baseline: 2.1199x; 1.1017x over previous
//
#include <hip/hip_runtime.h>
#include <math.h>
#include <stdint.h>

// Dims
#define BN    256      // B*N
#define UVD   49       // U*V
#define STD_  64       // S*T
#define CHD   8
#define AD    98
#define MD    128
#define CD    16

#define ZSZ   (BN*AD*MD*CD)      // 51,380,224 elements
#define T2SZ  (BN*AD*STD_*CHD)   // 12,845,056
#define PVSZ  (AD*MD*CD)         // 200,704

typedef unsigned short u16;
typedef __attribute__((ext_vector_type(8))) short bf16x8;
typedef __attribute__((ext_vector_type(4))) float f32x4;

// ---- bf16 helpers (internal storage bf16, compute fp32) ----
__device__ __forceinline__ float bf2f(u16 u) {
    return __builtin_bit_cast(float, ((uint32_t)u) << 16);
}
__device__ __forceinline__ float bflo(uint32_t u) {
    return __builtin_bit_cast(float, u << 16);
}
__device__ __forceinline__ float bfhi(uint32_t u) {
    return __builtin_bit_cast(float, u & 0xFFFF0000u);
}
__device__ __forceinline__ uint32_t packbf(float lo, float hi) {  // RNE pack 2 fp32 -> 2 bf16
    uint32_t a = __builtin_bit_cast(uint32_t, lo);
    uint32_t b = __builtin_bit_cast(uint32_t, hi);
    a = (a + 0x7FFFu + ((a >> 16) & 1u)) >> 16;
    b = (b + 0x7FFFu + ((b >> 16) & 1u)) >> 16;
    return a | (b << 16);
}
__device__ __forceinline__ u16 bf1(float f) {   // RNE fp32 -> bf16
    uint32_t a = __builtin_bit_cast(uint32_t, f);
    a = (a + 0x7FFFu + ((a >> 16) & 1u)) >> 16;
    return (u16)a;
}

__device__ __forceinline__ void fma4(float4& a, const float4& v, float s) {
    a.x = fmaf(v.x, s, a.x); a.y = fmaf(v.y, s, a.y);
    a.z = fmaf(v.z, s, a.z); a.w = fmaf(v.w, s, a.w);
}

__device__ __forceinline__ uint32_t hsh(uint32_t x) {
    x ^= x >> 16; x *= 0x7feb352dU;
    x ^= x >> 15; x *= 0x846ca68bU;
    x ^= x >> 16; return x;
}

__device__ __forceinline__ float blockReduceSum256(float s) {
    __shared__ float sw[4];
    #pragma unroll
    for (int o = 32; o > 0; o >>= 1) s += __shfl_down(s, o, 64);
    int lane = threadIdx.x & 63, wi = threadIdx.x >> 6;
    if (lane == 0) sw[wi] = s;
    __syncthreads();
    return sw[0] + sw[1] + sw[2] + sw[3];
}

// ---------------- prep: fragment-ordered ds/Ga (bf16) + Gram matrices ----------------

__global__ __launch_bounds__(256) void k_prep(const float* __restrict__ da, const float* __restrict__ ds,
                                              const float* __restrict__ dc,
                                              u16* __restrict__ dsAg, u16* __restrict__ dsCg,
                                              u16* __restrict__ GaBF,
                                              float* __restrict__ Ga, float* __restrict__ Gs,
                                              float* __restrict__ Gc) {
    int i = blockIdx.x * 256 + threadIdx.x;
    if (i < 8192) {                        // stage-A frags: A[m][k=st]
        int f = i >> 9, r = i & 511, L = r >> 3, j = r & 7;
        int mt = f >> 1, kc = f & 1;
        int m = mt * 16 + (L & 15), st = kc * 32 + (L >> 4) * 8 + j;
        dsAg[i] = bf1(ds[m * 64 + st]);
        return;
    }
    int i2 = i - 8192;
    if (i2 < 8192) {                       // stage-C frags: A2[st][k=m]
        int f = i2 >> 9, r = i2 & 511, L = r >> 3, j = r & 7;
        int mt2 = f >> 2, kc = f & 3;
        int st = mt2 * 16 + (L & 15), m = kc * 32 + (L >> 4) * 8 + j;
        dsCg[i2] = bf1(ds[m * 64 + st]);
        return;
    }
    int jg = i2 - 8192;
    if (jg < 9604) {                       // Ga 98x98 (symmetric) fp32
        int a = jg / 98, b = jg % 98;
        float s = 0.f;
        for (int uv = 0; uv < 49; ++uv) s = fmaf(da[a * 49 + uv], da[b * 49 + uv], s);
        Ga[jg] = s;
        return;
    }
    int k = jg - 9604;
    if (k < 16384) {                       // Gs 128x128
        int m = k >> 7, n = k & 127;
        float s = 0.f;
        for (int st = 0; st < 64; ++st) s = fmaf(ds[m * 64 + st], ds[n * 64 + st], s);
        Gs[k] = s;
        return;
    }
    int l = k - 16384;
    if (l < 256) {                         // Gc 16x16
        int c = l >> 4, d = l & 15;
        float s = 0.f;
        for (int h = 0; h < 8; ++h) s = fmaf(dc[c * 8 + h], dc[d * 8 + h], s);
        Gc[l] = s;
        return;
    }
    int gb = l - 256;
    if (gb < 16384) {                      // GaBF: B[k=a'][n=a] frags, 32 frags (nt 0..7, kc 0..3)
        int f = gb >> 9, r = gb & 511, L = r >> 3, j = r & 7;
        int nt = f >> 2, kc = f & 3;
        int a = nt * 16 + (L & 15), ap = kc * 32 + (L >> 4) * 8 + j;
        float v = 0.f;
        if (a < 98 && ap < 98) {
            float s = 0.f;
            for (int uv = 0; uv < 49; ++uv) s = fmaf(da[ap * 49 + uv], da[a * 49 + uv], s);
            v = s;
        }
        GaBF[gb] = bf1(v);
    }
}

// ---------------- one-time: xan = -adj_a(x), h-major bf16 ----------------

__global__ __launch_bounds__(256) void k_xa(const float* __restrict__ xg, const float* __restrict__ da,
                                            u16* __restrict__ xan) {
    __shared__ float l_r[49 * 68];     // 13.0 KB
    int ch = blockIdx.x, bn = blockIdx.y, t = threadIdx.x;   // ch = h (0..7)
    int base = ch * 64;
    size_t xbase = (size_t)bn * 25088;
    for (int e2 = t; e2 < 1568; e2 += 256) {
        int uv = e2 >> 5, i2 = (e2 & 31) * 2;
        float x0 = xg[xbase + uv * 512 + i2 * 8 + ch];
        float x1 = xg[xbase + uv * 512 + (i2 + 1) * 8 + ch];
        l_r[uv * 68 + i2]     = -x0;
        l_r[uv * 68 + i2 + 1] = -x1;
    }
    __syncthreads();
    for (int e2 = t; e2 < 3136; e2 += 256) {
        int a = e2 >> 5, i2 = (e2 & 31) * 2;
        float s0 = 0.f, s1 = 0.f;
        for (int uv = 0; uv < 49; ++uv) {
            float w = da[a * 49 + uv];
            s0 = fmaf(l_r[uv * 68 + i2], w, s0);
            s1 = fmaf(l_r[uv * 68 + i2 + 1], w, s1);
        }
        *(uint32_t*)&xan[(size_t)(bn * 98 + a) * 512 + base + i2] = packbf(s0, s1);
    }
}

// ---------------- joint 10-iter power iteration (fused, lazy-normalized) ----------------

__global__ __launch_bounds__(256) void k_v0(float* __restrict__ wv, float* __restrict__ part) {
    int b = blockIdx.x, t = threadIdx.x;
    float ssq = 0.f;
    for (int i = b * 1568 + t; i < (b + 1) * 1568; i += 256) {
        uint32_t h1 = hsh((uint32_t)(i * 2 + 1));
        uint32_t h2 = hsh((uint32_t)(i * 2 + 2) ^ 0x9e3779b9U);
        float u1 = ((float)h1 + 1.0f) * (1.0f / 4294967808.0f);
        float u2 = (float)h2 * (1.0f / 4294967296.0f);
        float g = sqrtf(-2.f * logf(u1)) * cosf(6.28318530718f * u2);
        wv[i] = g;
        ssq += g * g;
    }
    float tot = blockReduceSum256(ssq);
    if (t == 0) part[b] = tot;
}

__global__ __launch_bounds__(256) void k_pA(const float* __restrict__ wv, const float* __restrict__ part,
                                            const float* __restrict__ Gc, const float* __restrict__ Gs,
                                            float* __restrict__ w2) {
    __shared__ float lv[2048];
    __shared__ float lw1[2048];
    int a = blockIdx.x, t = threadIdx.x;
    float s = (t < 128) ? part[t] : 0.f;
    float tot = blockReduceSum256(s);
    float inv = 1.f / (sqrtf(tot) + 1e-12f);
    for (int e = t; e < 2048; e += 256) lv[e] = wv[a * 2048 + e] * inv;
    __syncthreads();
    if (t < 128) {
        int m = t;
        float vv[16];
        #pragma unroll
        for (int c = 0; c < 16; ++c) vv[c] = lv[m * 16 + c];
        #pragma unroll
        for (int d = 0; d < 16; ++d) {
            float acc = 0.f;
            #pragma unroll
            for (int c = 0; c < 16; ++c) acc = fmaf(vv[c], Gc[c * 16 + d], acc);
            lw1[m * 16 + d] = acc;
        }
    }
    __syncthreads();
    {
        int n = t >> 1, d0 = (t & 1) * 8;
        float acc[8];
        #pragma unroll
        for (int k = 0; k < 8; ++k) acc[k] = 0.f;
        for (int m = 0; m < 128; ++m) {
            float gsv = Gs[m * 128 + n];
            float4 w0 = *(const float4*)&lw1[m * 16 + d0];
            float4 w1v = *(const float4*)&lw1[m * 16 + d0 + 4];
            acc[0] = fmaf(w0.x, gsv, acc[0]); acc[1] = fmaf(w0.y, gsv, acc[1]);
            acc[2] = fmaf(w0.z, gsv, acc[2]); acc[3] = fmaf(w0.w, gsv, acc[3]);
            acc[4] = fmaf(w1v.x, gsv, acc[4]); acc[5] = fmaf(w1v.y, gsv, acc[5]);
            acc[6] = fmaf(w1v.z, gsv, acc[6]); acc[7] = fmaf(w1v.w, gsv, acc[7]);
        }
        float* op = &w2[a * 2048 + n * 16 + d0];
        *(float4*)op = make_float4(acc[0], acc[1], acc[2], acc[3]);
        *(float4*)(op + 4) = make_float4(acc[4], acc[5], acc[6], acc[7]);
    }
}

__global__ __launch_bounds__(256) void k_pB(const float* __restrict__ w2, const float* __restrict__ Ga,
                                            float* __restrict__ wv, float* __restrict__ part) {
    __shared__ float gal[AD * AD];     // 38.4 KB
    __shared__ float w2n[AD * CD];     // 6.3 KB
    int n = blockIdx.x, t = threadIdx.x;
    for (int e = t; e < AD * AD; e += 256) gal[e] = Ga[e];
    for (int e = t; e < AD * CD; e += 256) {
        int aa = e >> 4, d = e & 15;
        w2n[e] = w2[aa * 2048 + n * 16 + d];
    }
    __syncthreads();
    float ssq = 0.f;
    for (int e = t; e < AD * CD; e += 256) {
        int b = e >> 4, d = e & 15;
        float acc = 0.f;
        for (int aa = 0; aa < 98; ++aa) acc = fmaf(w2n[aa * 16 + d], gal[aa * 98 + b], acc);
        wv[b * 2048 + n * 16 + d] = acc;
        ssq += acc * acc;
    }
    float tot = blockReduceSum256(ssq);
    if (t == 0) part[n] = tot;
}

__global__ __launch_bounds__(256) void k_L(const float* __restrict__ part, float* __restrict__ scal) {
    int t = threadIdx.x;
    float s = (t < 128) ? part[t] : 0.f;
    float tot = blockReduceSum256(s);
    if (t == 0) {
        float L = fmaxf(sqrtf(tot), 1e-6f);
        scal[1] = 1.f / L;      // step
        scal[2] = 0.1f / L;     // thr = COUPLE/L
    }
}

// ---------------- FISTA kernels ----------------
// t2 layout h-major: t2[p][h*64 + st], bf16.

// j=1: t2 = xan
__global__ __launch_bounds__(256) void k_copy(const u16* __restrict__ src, u16* __restrict__ dst) {
    size_t i = (size_t)blockIdx.x * 256 + threadIdx.x;
    ((uint4*)dst)[i] = ((const uint4*)src)[i];
}

// MFMA angular: t2_new[bn,a,e] = sum_a' Ga[a,a']*t2[bn,a',e] + xan[bn,a,e], per (e-chunk 128, bn).
__global__ __launch_bounds__(256) void k_angA(u16* t2g, const u16* __restrict__ GaBF,
                                              const u16* __restrict__ xan) {
    __shared__ short ltT[128 * 136];   // 34.8 KB, e-rows, stride 136
    int ec = blockIdx.x, bn = blockIdx.y, t = threadIdx.x;
    int w = t >> 6, L = t & 63, quad = L >> 4, n = L & 15;
    size_t rowbase = (size_t)bn * 98 * 512 + ec * 128;

    // stage: load t2 chunk (98 a' x 128 e), transpose into ltT[e][a']
    for (int i = t; i < 1568; i += 256) {
        int ap = i >> 4, e8 = (i & 15) * 8;
        uint4 v = *(const uint4*)&t2g[rowbase + (size_t)ap * 512 + e8];
        u16 e0 = (u16)(v.x & 0xFFFF), e1 = (u16)(v.x >> 16);
        u16 e2 = (u16)(v.y & 0xFFFF), e3 = (u16)(v.y >> 16);
        u16 e4 = (u16)(v.z & 0xFFFF), e5 = (u16)(v.z >> 16);
        u16 e6 = (u16)(v.w & 0xFFFF), e7 = (u16)(v.w >> 16);
        ltT[(e8 + 0) * 136 + ap] = e0; ltT[(e8 + 1) * 136 + ap] = e1;
        ltT[(e8 + 2) * 136 + ap] = e2; ltT[(e8 + 3) * 136 + ap] = e3;
        ltT[(e8 + 4) * 136 + ap] = e4; ltT[(e8 + 5) * 136 + ap] = e5;
        ltT[(e8 + 6) * 136 + ap] = e6; ltT[(e8 + 7) * 136 + ap] = e7;
    }
    // zero K-padding columns a' = 98..129 (A-frags read k up to 127)
    for (int i = t; i < 128 * 32; i += 256) {
        int e = i >> 5, c = 98 + (i & 31);
        ltT[e * 136 + c] = 0;
    }
    __syncthreads();

    int nt0 = w * 2, nt1 = w * 2 + 1;
    f32x4 acc0[8], acc1[8];
    #pragma unroll
    for (int mt = 0; mt < 8; ++mt) { acc0[mt] = (f32x4){0,0,0,0}; acc1[mt] = (f32x4){0,0,0,0}; }
    #pragma unroll
    for (int kc = 0; kc < 4; ++kc) {
        bf16x8 B0 = *(const bf16x8*)&GaBF[(nt0 * 4 + kc) * 512 + L * 8];
        bf16x8 B1 = *(const bf16x8*)&GaBF[(nt1 * 4 + kc) * 512 + L * 8];
        #pragma unroll
        for (int mt = 0; mt < 8; ++mt) {
            bf16x8 A = *(const bf16x8*)&ltT[(mt * 16 + n) * 136 + kc * 32 + quad * 8];
            acc0[mt] = __builtin_amdgcn_mfma_f32_16x16x32_bf16(A, B0, acc0[mt], 0, 0, 0);
            acc1[mt] = __builtin_amdgcn_mfma_f32_16x16x32_bf16(A, B1, acc1[mt], 0, 0, 0);
        }
    }

    #pragma unroll
    for (int half = 0; half < 2; ++half) {
        int a = (half ? nt1 : nt0) * 16 + n;
        if (a < 98) {
            #pragma unroll
            for (int mt = 0; mt < 8; ++mt) {
                f32x4 acc = half ? acc1[mt] : acc0[mt];
                size_t idx = rowbase + (size_t)a * 512 + mt * 16 + quad * 4;
                uint2 xv = *(const uint2*)&xan[idx];
                float v0 = acc[0] + bflo(xv.x), v1 = acc[1] + bfhi(xv.x);
                float v2 = acc[2] + bflo(xv.y), v3 = acc[3] + bfhi(xv.y);
                *(uint2*)&t2g[idx] = make_uint2(packbf(v0, v1), packbf(v2, v3));
            }
        }
    }
}

// MFMA-fused adj_s + dc^T + FISTA + dc + recon_s. Block = 4 waves x 2 slices = 8 slices.
// l_t1b now bf16 (halves LDS 50->34 KB -> 4 blocks/CU).
__global__ __launch_bounds__(256) void k_fused(u16* t2g,
                                               const u16* __restrict__ dsAg, const u16* __restrict__ dsCg,
                                               const float* __restrict__ dcg, const float* __restrict__ scal,
                                               const u16* __restrict__ zc, u16* __restrict__ zp,
                                               float betaPrev, float beta, int first, int last) {
    __shared__ short l_t1b[8704];      // [col=slice*8+h][m] bf16, stride 136, 17.4 KB
    __shared__ short l_o[8704];        // [col][m] bf16, stride 136, 17.4 KB
    int t = threadIdx.x, w = t >> 6, L = t & 63;
    int quad = L >> 4, n = L & 15, s_n = n >> 3, h_n = n & 7;
    int P0 = blockIdx.x * 8 + w * 2;

    // pre-issue global loads: B-frags (stage A) + z streams
    bf16x8 Bf[2];
    #pragma unroll
    for (int kc = 0; kc < 2; ++kc)
        Bf[kc] = *(const bf16x8*)&t2g[(size_t)(P0 + s_n) * 512 + h_n * 64 + kc * 32 + quad * 8];
    uint4 zcr[8], zpr[8];
    bool haveZp = (!first) && (betaPrev != 0.0f);
    if (!first) {
        #pragma unroll
        for (int sl = 0; sl < 2; ++sl)
            #pragma unroll
            for (int mh = 0; mh < 2; ++mh) {
                size_t q = (size_t)(P0 + sl) * 2048 + (size_t)(mh * 64 + L) * 16;
                zcr[(sl * 2 + mh) * 2]     = *(const uint4*)&zc[q];
                zcr[(sl * 2 + mh) * 2 + 1] = *(const uint4*)&zc[q + 8];
            }
    }
    if (haveZp) {
        #pragma unroll
        for (int sl = 0; sl < 2; ++sl)
            #pragma unroll
            for (int mh = 0; mh < 2; ++mh) {
                size_t q = (size_t)(P0 + sl) * 2048 + (size_t)(mh * 64 + L) * 16;
                zpr[(sl * 2 + mh) * 2]     = *(const uint4*)&zp[q];
                zpr[(sl * 2 + mh) * 2 + 1] = *(const uint4*)&zp[q + 8];
            }
    }

    // ---- stage A (MFMA): A-frags from global (L1-hot) ----
    f32x4 accA[8];
    #pragma unroll
    for (int mt = 0; mt < 8; ++mt) accA[mt] = (f32x4){0.f, 0.f, 0.f, 0.f};
    #pragma unroll
    for (int kc = 0; kc < 2; ++kc) {
        #pragma unroll
        for (int mt = 0; mt < 8; ++mt) {
            bf16x8 A = *(const bf16x8*)&dsAg[(mt * 2 + kc) * 512 + L * 8];
            accA[mt] = __builtin_amdgcn_mfma_f32_16x16x32_bf16(A, Bf[kc], accA[mt], 0, 0, 0);
        }
    }
    {
        int col = ((w * 2 + s_n) * 8 + h_n) * 136;
        #pragma unroll
        for (int mt = 0; mt < 8; ++mt) {
            uint2 pv = make_uint2(packbf(accA[mt][0], accA[mt][1]),
                                  packbf(accA[mt][2], accA[mt][3]));
            *(uint2*)&l_t1b[col + mt * 16 + quad * 4] = pv;
        }
    }
    __syncthreads();

    // ---- stage B (VALU pointwise FISTA), thread = m ----
    float step = scal[1], thr = scal[2];
    #pragma unroll
    for (int sl = 0; sl < 2; ++sl) {
        int slK = w * 2 + sl;
        #pragma unroll
        for (int mh = 0; mh < 2; ++mh) {
            int m = mh * 64 + L, ri = sl * 2 + mh;
            float tb[8];
            #pragma unroll
            for (int h = 0; h < 8; ++h) tb[h] = bf2f((u16)l_t1b[(slK * 8 + h) * 136 + m]);
            float g[16];
            #pragma unroll
            for (int c = 0; c < 16; ++c) {
                float s = 0.f;
                #pragma unroll
                for (int h = 0; h < 8; ++h) s = fmaf(tb[h], dcg[c * 8 + h], s);
                g[c] = s;
            }
            float zcv[16], zpv[16];
            #pragma unroll
            for (int c = 0; c < 16; ++c) { zcv[c] = 0.f; zpv[c] = 0.f; }
            if (!first) {
                uint4 a0 = zcr[ri * 2], a1 = zcr[ri * 2 + 1];
                zcv[0] = bflo(a0.x); zcv[1] = bfhi(a0.x); zcv[2] = bflo(a0.y); zcv[3] = bfhi(a0.y);
                zcv[4] = bflo(a0.z); zcv[5] = bfhi(a0.z); zcv[6] = bflo(a0.w); zcv[7] = bfhi(a0.w);
                zcv[8] = bflo(a1.x); zcv[9] = bfhi(a1.x); zcv[10] = bflo(a1.y); zcv[11] = bfhi(a1.y);
                zcv[12] = bflo(a1.z); zcv[13] = bfhi(a1.z); zcv[14] = bflo(a1.w); zcv[15] = bfhi(a1.w);
            }
            if (haveZp) {
                uint4 b0 = zpr[ri * 2], b1 = zpr[ri * 2 + 1];
                zpv[0] = bflo(b0.x); zpv[1] = bfhi(b0.x); zpv[2] = bflo(b0.y); zpv[3] = bfhi(b0.y);
                zpv[4] = bflo(b0.z); zpv[5] = bfhi(b0.z); zpv[6] = bflo(b0.w); zpv[7] = bfhi(b0.w);
                zpv[8] = bflo(b1.x); zpv[9] = bfhi(b1.x); zpv[10] = bflo(b1.y); zpv[11] = bfhi(b1.y);
                zpv[12] = bflo(b1.z); zpv[13] = bfhi(b1.z); zpv[14] = bflo(b1.w); zpv[15] = bfhi(b1.w);
            }
            float zn[16], src[16];
            #pragma unroll
            for (int c = 0; c < 16; ++c) {
                float y  = fmaf(betaPrev, zcv[c] - zpv[c], zcv[c]);
                float pv = fmaf(-step, g[c], y);
                float av = fabsf(pv) - thr;
                float z1 = (av > 0.f) ? copysignf(av, pv) : 0.f;
                zn[c] = z1;
                src[c] = last ? z1 : fmaf(beta, z1 - zcv[c], z1);
            }
            if (!last) {
                size_t q = (size_t)(P0 + sl) * 2048 + (size_t)m * 16;
                uint4 o0, o1;
                o0.x = packbf(zn[0], zn[1]);  o0.y = packbf(zn[2], zn[3]);
                o0.z = packbf(zn[4], zn[5]);  o0.w = packbf(zn[6], zn[7]);
                o1.x = packbf(zn[8], zn[9]);  o1.y = packbf(zn[10], zn[11]);
                o1.z = packbf(zn[12], zn[13]); o1.w = packbf(zn[14], zn[15]);
                *(uint4*)&zp[q] = o0;
                *(uint4*)&zp[q + 8] = o1;
            }
            #pragma unroll
            for (int h = 0; h < 8; ++h) {
                float s = 0.f;
                #pragma unroll
                for (int c = 0; c < 16; ++c) s = fmaf(src[c], dcg[c * 8 + h], s);
                l_o[(slK * 8 + h) * 136 + m] = (short)bf1(s);
            }
        }
    }
    __syncthreads();

    // ---- stage C (MFMA): A2-frags from global ----
    f32x4 accC[4];
    #pragma unroll
    for (int mt2 = 0; mt2 < 4; ++mt2) accC[mt2] = (f32x4){0.f, 0.f, 0.f, 0.f};
    #pragma unroll
    for (int kc = 0; kc < 4; ++kc) {
        bf16x8 B2 = *(const bf16x8*)&l_o[((w * 2 + s_n) * 8 + h_n) * 136 + kc * 32 + quad * 8];
        #pragma unroll
        for (int mt2 = 0; mt2 < 4; ++mt2) {
            bf16x8 A2 = *(const bf16x8*)&dsCg[(mt2 * 4 + kc) * 512 + L * 8];
            accC[mt2] = __builtin_amdgcn_mfma_f32_16x16x32_bf16(A2, B2, accC[mt2], 0, 0, 0);
        }
    }
    #pragma unroll
    for (int mt2 = 0; mt2 < 4; ++mt2) {
        uint2 ov = make_uint2(packbf(accC[mt2][0], accC[mt2][1]),
                              packbf(accC[mt2][2], accC[mt2][3]));
        *(uint2*)&t2g[(size_t)(P0 + s_n) * 512 + h_n * 64 + mt2 * 16 + quad * 4] = ov;
    }
}

// Final angular recon from h-major t2 -> st-major fp32 out
__global__ __launch_bounds__(128) void k_recon_out(const u16* __restrict__ t2, const float* __restrict__ da,
                                                   float* __restrict__ out) {
    __shared__ float lt2[16 * 512];
    __shared__ float l_t[7 * 520];
    int uvg = blockIdx.x, bn = blockIdx.y, t = threadIdx.x;
    float4 acc[7];
    #pragma unroll
    for (int u = 0; u < 7; ++u) acc[u] = make_float4(0.f, 0.f, 0.f, 0.f);
    for (int c0 = 0; c0 < AD; c0 += 16) {
        int na = min(16, AD - c0);
        for (int e8 = t; e8 < na * 64; e8 += 128) {
            uint4 v = *(const uint4*)&t2[(size_t)(bn * AD + c0) * 512 + e8 * 8];
            float* d = &lt2[e8 * 8];
            d[0] = bflo(v.x); d[1] = bfhi(v.x); d[2] = bflo(v.y); d[3] = bfhi(v.y);
            d[4] = bflo(v.z); d[5] = bfhi(v.z); d[6] = bflo(v.w); d[7] = bfhi(v.w);
        }
        __syncthreads();
        for (int al = 0; al < na; ++al) {
            float4 rv = *(const float4*)&lt2[al * 512 + t * 4];
            int a = c0 + al;
            #pragma unroll
            for (int u = 0; u < 7; ++u)
                fma4(acc[u], rv, da[a * 49 + uvg * 7 + u]);
        }
        __syncthreads();
    }
    #pragma unroll
    for (int u = 0; u < 7; ++u)
        *(float4*)&l_t[u * 520 + t * 4] = acc[u];
    __syncthreads();
    for (int f = t; f < 896; f += 128) {
        int u = f >> 7, e4 = (f & 127) * 4;
        int st = e4 >> 3, h0 = e4 & 7;
        float4 o;
        o.x = l_t[u * 520 + (h0 + 0) * 64 + st];
        o.y = l_t[u * 520 + (h0 + 1) * 64 + st];
        o.z = l_t[u * 520 + (h0 + 2) * 64 + st];
        o.w = l_t[u * 520 + (h0 + 3) * 64 + st];
        *(float4*)&out[(size_t)bn * 25088 + (size_t)(uvg * 7 + u) * 512 + e4] = o;
    }
}

// ---------------- launcher ----------------

extern "C" void kernel_launch(void* const* d_in, const int* in_sizes, int n_in,
                              void* d_out, int out_size, void* d_ws, size_t ws_size,
                              hipStream_t stream) {
    const float* x  = (const float*)d_in[0];
    const float* da = (const float*)d_in[1];
    const float* ds = (const float*)d_in[2];
    const float* dc = (const float*)d_in[3];
    float* out = (float*)d_out;

    char* base = (char*)d_ws;
    u16* Za   = (u16*)base; base += (size_t)ZSZ * 2;    // 102.76 MB
    u16* Zb   = (u16*)base; base += (size_t)ZSZ * 2;    // 102.76 MB
    u16* t2   = (u16*)base; base += (size_t)T2SZ * 2;   // 25.69 MB
    u16* xan  = (u16*)base; base += (size_t)T2SZ * 2;   // 25.69 MB
    u16* dsAg = (u16*)base; base += 8192 * 2;
    u16* dsCg = (u16*)base; base += 8192 * 2;
    u16* GaBF = (u16*)base; base += 16384 * 2;
    float* fb = (float*)base;
    size_t off = 0;
    float* Ga   = fb + off; off += 9604;
    float* Gs   = fb + off; off += 16384;
    float* Gc   = fb + off; off += 256;
    float* w2   = fb + off; off += PVSZ;
    float* wv   = fb + off; off += PVSZ;
    float* part = fb + off; off += 128;
    float* scal = fb + off; off += 4;
    (void)ws_size; (void)in_sizes; (void)n_in; (void)out_size;

    // ---- prep + xan + power iteration ----
    k_prep<<<231, 256, 0, stream>>>(da, ds, dc, dsAg, dsCg, GaBF, Ga, Gs, Gc);
    k_xa<<<dim3(8, 256), 256, 0, stream>>>(x, da, xan);
    k_v0<<<128, 256, 0, stream>>>(wv, part);
    for (int it = 0; it < 10; ++it) {
        k_pA<<<98, 256, 0, stream>>>(wv, part, Gc, Gs, w2);
        k_pB<<<128, 256, 0, stream>>>(w2, Ga, wv, part);
    }
    k_L<<<1, 256, 0, stream>>>(part, scal);

    // ---- beta schedule ----
    float betaArr[16];
    betaArr[0] = 0.f;
    double tprev = 1.0;
    for (int j = 1; j <= 15; ++j) {
        double tn = (1.0 + sqrt(1.0 + 4.0 * tprev * tprev)) * 0.5;
        betaArr[j] = (float)((tprev - 1.0) / tn);
        tprev = tn;
    }

    // ---- FISTA: 15 iterations ----
    u16* zbufs[2] = { Za, Zb };
    for (int j = 1; j <= 15; ++j) {
        if (j == 1) {
            k_copy<<<T2SZ / (256 * 8), 256, 0, stream>>>(xan, t2);
        } else {
            k_angA<<<dim3(4, 256), 256, 0, stream>>>(t2, GaBF, xan);
        }
        const u16* zc = zbufs[1 - (j & 1)];   // z_{j-1}
        u16* zp = zbufs[j & 1];               // z_{j-2} -> becomes z_j
        k_fused<<<3136, 256, 0, stream>>>(t2, dsAg, dsCg, dc, scal, zc, zp,
                                          (j >= 2) ? betaArr[j - 1] : 0.f, betaArr[j],
                                          (j == 1) ? 1 : 0, (j == 15) ? 1 : 0);
    }

    // ---- final recon(z15) -> out ----
    k_recon_out<<<dim3(7, 256), 128, 0, stream>>>(t2, da, out);
}